// Round 14
// baseline (86.954 us; speedup 1.0000x reference)
//
#include <hip/hip_runtime.h>
#include <math.h>

#define NUM_A 90
#define RBINS 727      // 2*363 + 1
#define HDIM  256
#define WDIM  256
#define RMIN  181      // lowest bin ever touched
#define RACT  365      // active bins: 181..545
#define RMAX  545
#define TPB   768      // 184 bin-pairs x 4 row-parities = 736 active (+32 pad)
#define PH_ROWS 52
#define ROWSTR  260    // floats per row slot; 1040 B (16B-aligned); 260 % 32 = 4
#define NPH     5      // 52*4 + 48 = 256
#define TILE_N  (PH_ROWS * ROWSTR)   // 13520 floats = 54080 B

// ---------------- angle table: tab[2a]=cos, tab[2a+1]=sin ----------------
__global__ void angles_k(float* __restrict__ tab) {
    int a = threadIdx.x;
    if (a < NUM_A) {
        double th = (double)a * (3.14159265358979323846 / 90.0);
        tab[2 * a]     = (float)cos(th);
        tab[2 * a + 1] = (float)sin(th);
    }
}

// ---------------- transpose: maskT[b][x][y] = mask[b][y][x] ----------------
__global__ __launch_bounds__(256) void transpose_k(const float* __restrict__ in,
                                                   float* __restrict__ out) {
    __shared__ float tile[32][33];
    int b = blockIdx.z;
    const float* ib = in  + (size_t)b * (HDIM * WDIM);
    float*       ob = out + (size_t)b * (HDIM * WDIM);
    int x0 = blockIdx.x * 32, y0 = blockIdx.y * 32;
    int tx = threadIdx.x, ty = threadIdx.y;
#pragma unroll
    for (int j = ty; j < 32; j += 8)
        tile[j][tx] = ib[(size_t)(y0 + j) * WDIM + (x0 + tx)];
    __syncthreads();
#pragma unroll
    for (int j = ty; j < 32; j += 8)
        ob[(size_t)(x0 + j) * HDIM + (y0 + tx)] = tile[tx][j];
}

// 3-tap weight+accumulate: w_k = med3(1-u_k, 1+u_k, 0), u from fr = f0 - lo
// (exact). R11/R13-proven (absmax 1.0, graph-replay stable).
static __device__ __forceinline__ float tap3(float f0, float lo, float ci,
                                             float onems, float onepls,
                                             float v0, float v1, float v2,
                                             float acc) {
    float fr = f0 - lo;
    float a0 = fmaf(fr, -ci, onems), b0 = fmaf(fr, ci, onepls);
    acc = fmaf(v0, __builtin_amdgcn_fmed3f(a0, b0, 0.0f), acc);
    float a1 = a0 - ci, b1 = b0 + ci;
    acc = fmaf(v1, __builtin_amdgcn_fmed3f(a1, b1, 0.0f), acc);
    float a2 = a1 - ci, b2 = b1 + ci;
    acc = fmaf(v2, __builtin_amdgcn_fmed3f(a2, b2, 0.0f), acc);
    return acc;
}

// ---------------- LDS-staged gather hough: bin-pair lanes ----------------
// Lane owns bins (r0, r1 = r0+1) at rows j = m (mod 4). Windows differ by
// ainv = |1/ci| in [1, 1.41] -> combined span <= 5 contiguous taps starting
// at the lower-window bin A. Read v0..v4 once; B's 3 taps selected by
// d = iB - iA in {0,1,2} (clamps at image edges keep d <= 2 and consumed
// index <= 255; reads reach iA+4 <= 257 < ROWSTR, in-slot, unused values).
// Each bin's weights are EXACTLY the R13 math (own lo, own clamp, tap3).
__global__ __launch_bounds__(TPB, 6) void hough_lds_k(const float* __restrict__ srcA,
                                                      const float* __restrict__ srcB,
                                                      const float* __restrict__ tab,
                                                      float* __restrict__ out) {
    __shared__ float tile[TILE_N];
    int ba = blockIdx.x;
    int b  = ba / NUM_A;
    int a  = ba - b * NUM_A;

    float c = tab[2 * a], s = tab[2 * a + 1];
    bool  xs = fabsf(c) >= fabsf(s);       // solve axis = larger coeff
    float ci = xs ? c : s;                 // |ci| >= 0.707
    float cj = xs ? s : c;
    const float* src = (xs ? srcA : srcB) + (size_t)b * (HDIM * WDIM);

    int   tid = threadIdx.x;
    int   pp  = tid >> 2;                  // bin pair index (active: 0..182)
    int   m   = tid & 3;                   // row parity: rows j == m (mod 4)
    int   r0  = RMIN + 2 * pp;
    int   r1  = r0 + 1;
    bool  act = (r0 <= RMAX);              // pp <= 182

    // active j-range for the PAIR: t-span hits (r0-1, r1+1)
    float p = fminf(-128.0f * ci, 127.0f * ci);
    float q = fmaxf(-128.0f * ci, 127.0f * ci);
    float rlo = (float)r0 - 1.0f, rhi = (float)r1 + 1.0f;
    int jl, jh;
    float acj = fabsf(cj);
    if (acj > 1e-5f) {
        float invj = 1.0f / cj;
        float jA = (rhi - p - 363.0f) * invj + 128.0f;
        float jB = (rlo - q - 363.0f) * invj + 128.0f;
        float jmn = fminf(jA, jB) - 1.0f;   // widen: weights self-guard extras
        float jmx = fmaxf(jA, jB) + 2.0f;
        jl = (int)fminf(fmaxf(jmn, 0.0f), 256.0f);
        jh = (int)fminf(fmaxf(jmx, 0.0f), 256.0f);
    } else {                               // cj ~ 0: t j-independent
        bool any = (363.0f + q > rlo) && (363.0f + p < rhi);
        jl = 0; jh = any ? 256 : 0;
    }
    if (!act) { jl = 0; jh = 0; }

    // window anchor A = bin with the smaller lo (lo_r increases with r iff inv>0)
    float inv  = 1.0f / ci;
    float sgn  = (ci > 0.0f) ? -1.0f : 1.0f;
    int   irA  = (inv > 0.0f) ? r0 : r1;
    int   irB  = (inv > 0.0f) ? r1 : r0;
    float rAf  = (float)irA;
    float LOA0 = (sgn - (363.0f - rAf - 128.0f * cj - 128.0f * ci)) * inv;
    float dlo  = -cj * inv;                // |dlo| <= 1
    float ainv = fabsf(inv);               // loB = loA + ainv
    float onems = 1.0f - sgn;              // 2 (ci>0) or 0 (ci<0)
    float onepls = 1.0f + sgn;             // 0 (ci>0) or 2 (ci<0)
    float dlo4 = 4.0f * dlo;

    // first row >= jl with parity m
    int start = jl + ((m - jl) & 3);

    int wid = tid >> 6, lane = tid & 63;
    float accA = 0.0f, accB = 0.0f;
    for (int ph = 0; ph < NPH; ++ph) {
        int phb   = ph * PH_ROWS;
        int nrows = (phb + PH_ROWS <= 256) ? PH_ROWS : (256 - phb);
        if (ph) __syncthreads();           // prior-phase LDS reads complete
        // stage: one wave stages one 256-float row (64 lanes x 16B);
        // dest base = tile + sl*260 floats = sl*1040 B (16B-aligned)
        for (int sl = wid; sl < nrows; sl += 12) {
            const float* grow = src + (size_t)(phb + sl) * 256 + lane * 4;
            float* lrow = tile + sl * ROWSTR + lane * 4;
            __builtin_amdgcn_global_load_lds(
                (const __attribute__((address_space(1))) unsigned int*)grow,
                (__attribute__((address_space(3))) unsigned int*)lrow, 16, 0, 0);
        }
        __syncthreads();                   // staging complete (vmcnt drained)

        int pstart = phb + ((m - phb) & 3);
        int jsp = start > pstart ? start : pstart;
        int jep = jh < phb + nrows ? jh : phb + nrows;
        if (jep <= jsp) continue;
        int cnt = (jep - jsp + 3) >> 2;    // rows: jsp, jsp+4, ...

        float loA = fmaf((float)jsp, dlo, LOA0);
        int rowf = (jsp - phb) * ROWSTR;
        int npair = cnt >> 1;
        for (int pr = 0; pr < npair; ++pr) {
            float lo0 = loA;
            float lo1 = loA + dlo4;
            loA = lo1 + dlo4;
            // --- row 0 ---
            float lb0 = lo0 + ainv;
            float fA0 = __builtin_amdgcn_fmed3f(ceilf(lo0), 0.0f, 253.0f);
            float fB0 = __builtin_amdgcn_fmed3f(ceilf(lb0), 0.0f, 253.0f);
            int iA0 = (int)fA0, iB0 = (int)fB0;
            const float* P0 = tile + rowf + iA0;
            float x0 = P0[0], x1 = P0[1], x2 = P0[2], x3 = P0[3], x4 = P0[4];
            // --- row 1 ---
            float lb1 = lo1 + ainv;
            float fA1 = __builtin_amdgcn_fmed3f(ceilf(lo1), 0.0f, 253.0f);
            float fB1 = __builtin_amdgcn_fmed3f(ceilf(lb1), 0.0f, 253.0f);
            int iA1 = (int)fA1, iB1 = (int)fB1;
            const float* P1 = tile + rowf + 4 * ROWSTR + iA1;
            float y0 = P1[0], y1 = P1[1], y2 = P1[2], y3 = P1[3], y4 = P1[4];
            rowf += 8 * ROWSTR;

            int d0 = iB0 - iA0;            // in {0,1,2}
            bool d01 = d0 >= 1, d02 = d0 >= 2;
            float s00 = d01 ? x1 : x0; s00 = d02 ? x2 : s00;
            float s01 = d01 ? x2 : x1; s01 = d02 ? x3 : s01;
            float s02 = d01 ? x3 : x2; s02 = d02 ? x4 : s02;
            accA = tap3(fA0, lo0, ci, onems, onepls, x0, x1, x2, accA);
            accB = tap3(fB0, lb0, ci, onems, onepls, s00, s01, s02, accB);

            int d1 = iB1 - iA1;
            bool d11 = d1 >= 1, d12 = d1 >= 2;
            float s10 = d11 ? y1 : y0; s10 = d12 ? y2 : s10;
            float s11 = d11 ? y2 : y1; s11 = d12 ? y3 : s11;
            float s12 = d11 ? y3 : y2; s12 = d12 ? y4 : s12;
            accA = tap3(fA1, lo1, ci, onems, onepls, y0, y1, y2, accA);
            accB = tap3(fB1, lb1, ci, onems, onepls, s10, s11, s12, accB);
        }
        if (cnt & 1) {                     // tail: one row
            float lb = loA + ainv;
            float fA = __builtin_amdgcn_fmed3f(ceilf(loA), 0.0f, 253.0f);
            float fB = __builtin_amdgcn_fmed3f(ceilf(lb), 0.0f, 253.0f);
            int iA = (int)fA, iB = (int)fB;
            const float* P0 = tile + rowf + iA;
            float x0 = P0[0], x1 = P0[1], x2 = P0[2], x3 = P0[3], x4 = P0[4];
            int d = iB - iA;
            bool dd1 = d >= 1, dd2 = d >= 2;
            float s0 = dd1 ? x1 : x0; s0 = dd2 ? x2 : s0;
            float s1 = dd1 ? x2 : x1; s1 = dd2 ? x3 : s1;
            float s2 = dd1 ? x3 : x2; s2 = dd2 ? x4 : s2;
            accA = tap3(fA, loA, ci, onems, onepls, x0, x1, x2, accA);
            accB = tap3(fB, lb, ci, onems, onepls, s0, s1, s2, accB);
        }
    }

    // reduce the 4 row-parities (adjacent lanes), lane m==0 stores both bins
    accA += __shfl_xor(accA, 1);
    accA += __shfl_xor(accA, 2);
    accB += __shfl_xor(accB, 1);
    accB += __shfl_xor(accB, 2);
    if (m == 0) {
        float* o = out + (size_t)ba * RBINS;
        if (irA <= RMAX && act) o[irA] = accA;
        if (irB <= RMAX && act) o[irB] = accB;
    }
}

// ---------------- fallback (no workspace): R7-proven global-gather ----------------
typedef float f3v __attribute__((ext_vector_type(3)));
typedef f3v __attribute__((aligned(4))) f3u;
#define FB_GRP (368 * 4)

__global__ __launch_bounds__(256) void hough_fb_k(const float* __restrict__ src0,
                                                  float* __restrict__ out, int nba) {
    int gtid = blockIdx.x * 256 + threadIdx.x;
    int grp  = gtid / FB_GRP;
    if (grp >= nba) return;
    int k    = gtid - grp * FB_GRP;
    int ba   = __builtin_amdgcn_readfirstlane(grp);
    int b    = ba / NUM_A;
    int a    = ba - b * NUM_A;
    double th = (double)a * (3.14159265358979323846 / 90.0);
    float c = (float)cos(th), s = (float)sin(th);
    bool  xs = fabsf(c) >= fabsf(s);
    float ci = xs ? c : s, cj = xs ? s : c;
    const float* src = src0 + (size_t)b * (HDIM * WDIM);
    int   bin = k >> 2, m = k & 3;
    int   r = RMIN + bin;
    float rf = (float)r;
    bool  active = bin < RACT;
    float inv = 1.0f / ci, ainv = fabsf(inv);
    float p = fminf(-128.0f * ci, 127.0f * ci);
    float q = fmaxf(-128.0f * ci, 127.0f * ci);
    int jl, jh;
    float acj = fabsf(cj);
    if (acj > 1e-5f) {
        float invj = 1.0f / cj;
        float jA = (rf + 1.0f - p - 363.0f) * invj + 128.0f;
        float jB = (rf - 1.0f - q - 363.0f) * invj + 128.0f;
        jl = (int)fminf(fmaxf(fminf(jA, jB) - 1.0f, 0.0f), 256.0f);
        jh = (int)fminf(fmaxf(fmaxf(jA, jB) + 2.0f, 0.0f), 256.0f);
    } else {
        bool any = (363.0f + q > rf - 1.01f) && (363.0f + p < rf + 1.01f);
        jl = 0; jh = any ? 256 : 0;
    }
    if (!active) { jl = 0; jh = 0; }
    int len = jh - jl;
    int js = jl + ((m * len) >> 2);
    int je = jl + (((m + 1) * len) >> 2);
    float dlo = -cj * inv;
    float LO0 = 128.0f + (rf - 363.0f) * inv - ainv + 128.0f * cj * inv;
    float Z0  = 363.0f - rf - 128.0f * cj - 128.0f * ci;
    float ci2 = ci + ci;
    float acc = 0.0f;
    for (int j = js; j < je; ++j) {
        float jf  = (float)j;
        float lo0 = fmaf(jf, dlo, LO0);
        float z0  = fmaf(jf, cj, Z0);
        float f0  = __builtin_amdgcn_fmed3f(ceilf(lo0), 0.0f, 253.0f);
        int   i0  = (int)f0;
        float a0, b0, c0;
        if (xs) {
            f3v mm = *(const f3u*)(src + ((size_t)j << 8) + i0);
            a0 = mm.x; b0 = mm.y; c0 = mm.z;
        } else {
            const float* p0 = src + j + ((size_t)i0 << 8);
            a0 = p0[0]; b0 = p0[256]; c0 = p0[512];
        }
        float u0 = fmaf(f0, ci, z0);
        acc = fmaf(a0, fmaxf(1.0f - fabsf(u0), 0.0f), acc);
        acc = fmaf(b0, fmaxf(1.0f - fabsf(u0 + ci), 0.0f), acc);
        acc = fmaf(c0, fmaxf(1.0f - fabsf(u0 + ci2), 0.0f), acc);
    }
    acc += __shfl_xor(acc, 1);
    acc += __shfl_xor(acc, 2);
    if (active && m == 0)
        out[(size_t)ba * RBINS + r] = acc;
}

extern "C" void kernel_launch(void* const* d_in, const int* in_sizes, int n_in,
                              void* d_out, int out_size, void* d_ws, size_t ws_size,
                              hipStream_t stream) {
    const float* mask = (const float*)d_in[0];
    float* out = (float*)d_out;
    int B = in_sizes[0] / (HDIM * WDIM);   // 16
    int nba = B * NUM_A;

    size_t needT = (size_t)B * HDIM * WDIM * sizeof(float);
    size_t needW = needT + 2 * NUM_A * sizeof(float);
    int fast = (d_ws != nullptr && ws_size >= needW) ? 1 : 0;
    float* maskT = (float*)d_ws;
    float* tab   = (float*)((char*)d_ws + needT);

    // zero the never-touched rho bins once per call (also covers len==0 bins)
    hipMemsetAsync(d_out, 0, (size_t)out_size * sizeof(float), stream);

    if (fast) {
        transpose_k<<<dim3(WDIM / 32, HDIM / 32, B), dim3(32, 8), 0, stream>>>(mask, maskT);
        angles_k<<<1, 128, 0, stream>>>(tab);
        hough_lds_k<<<nba, TPB, 0, stream>>>(mask, maskT, tab, out);
    } else {
        int nthreads = nba * FB_GRP;
        hough_fb_k<<<(nthreads + 255) / 256, 256, 0, stream>>>(mask, out, nba);
    }
}

// Round 15
// 82.100 us; speedup vs baseline: 1.0591x; 1.0591x over previous
//
#include <hip/hip_runtime.h>
#include <math.h>

#define NUM_A 90
#define RBINS 727      // 2*363 + 1
#define HDIM  256
#define WDIM  256
#define RMIN  181      // lowest bin ever touched
#define RACT  365      // active bins: 181..545
#define TPB   768      // 368 bins x 2 parity-strips (+pad) = 12 waves
#define PH_ROWS 52
#define ROWSTR  260    // floats per row slot; 1040 B (16B-aligned); 260 % 32 = 4
#define NPH     5      // 52*4 + 48 = 256
#define TILE_N  (PH_ROWS * ROWSTR)   // 13520 floats = 54080 B

// ---------------- angle table: tab[2a]=cos, tab[2a+1]=sin ----------------
__global__ void angles_k(float* __restrict__ tab) {
    int a = threadIdx.x;
    if (a < NUM_A) {
        double th = (double)a * (3.14159265358979323846 / 90.0);
        tab[2 * a]     = (float)cos(th);
        tab[2 * a + 1] = (float)sin(th);
    }
}

// ---------------- transpose: maskT[b][x][y] = mask[b][y][x] ----------------
__global__ __launch_bounds__(256) void transpose_k(const float* __restrict__ in,
                                                   float* __restrict__ out) {
    __shared__ float tile[32][33];
    int b = blockIdx.z;
    const float* ib = in  + (size_t)b * (HDIM * WDIM);
    float*       ob = out + (size_t)b * (HDIM * WDIM);
    int x0 = blockIdx.x * 32, y0 = blockIdx.y * 32;
    int tx = threadIdx.x, ty = threadIdx.y;
#pragma unroll
    for (int j = ty; j < 32; j += 8)
        tile[j][tx] = ib[(size_t)(y0 + j) * WDIM + (x0 + tx)];
    __syncthreads();
#pragma unroll
    for (int j = ty; j < 32; j += 8)
        ob[(size_t)(x0 + j) * HDIM + (y0 + tx)] = tile[tx][j];
}

// 3-tap weight+accumulate: w_k = med3(1-u_k, 1+u_k, 0), u from fr = f0 - lo
// (exact). R11/R13-proven (absmax 1.0, graph-replay stable).
static __device__ __forceinline__ float tap3(float f0, float lo, float ci,
                                             float onems, float onepls,
                                             float v0, float v1, float v2,
                                             float acc) {
    float fr = f0 - lo;
    float a0 = fmaf(fr, -ci, onems), b0 = fmaf(fr, ci, onepls);
    acc = fmaf(v0, __builtin_amdgcn_fmed3f(a0, b0, 0.0f), acc);
    float a1 = a0 - ci, b1 = b0 + ci;
    acc = fmaf(v1, __builtin_amdgcn_fmed3f(a1, b1, 0.0f), acc);
    float a2 = a1 - ci, b2 = b1 + ci;
    acc = fmaf(v2, __builtin_amdgcn_fmed3f(a2, b2, 0.0f), acc);
    return acc;
}

// ---------------- LDS-staged gather hough (R13 + 4-row unroll, dual acc) ----
__global__ __launch_bounds__(TPB, 6) void hough_lds_k(const float* __restrict__ srcA,
                                                      const float* __restrict__ srcB,
                                                      const float* __restrict__ tab,
                                                      float* __restrict__ out) {
    __shared__ float tile[TILE_N];
    int ba = blockIdx.x;
    int b  = ba / NUM_A;
    int a  = ba - b * NUM_A;

    float c = tab[2 * a], s = tab[2 * a + 1];
    bool  xs = fabsf(c) >= fabsf(s);       // solve axis = larger coeff
    float ci = xs ? c : s;
    float cj = xs ? s : c;
    const float* src = (xs ? srcA : srcB) + (size_t)b * (HDIM * WDIM);

    int   tid = threadIdx.x;
    int   bin = tid >> 1;                  // 2 parity strips per bin
    int   m   = tid & 1;                   // lane parity: rows j with (j&1)==m
    int   r   = RMIN + bin;
    float rf  = (float)r;
    bool  active = bin < RACT;

    // active j-range (R8/R11-proven): rows whose t-span hits (r-1, r+1)
    float p = fminf(-128.0f * ci, 127.0f * ci);
    float q = fmaxf(-128.0f * ci, 127.0f * ci);
    int jl, jh;
    float acj = fabsf(cj);
    if (acj > 1e-5f) {
        float invj = 1.0f / cj;
        float jA = (rf + 1.0f - p - 363.0f) * invj + 128.0f;
        float jB = (rf - 1.0f - q - 363.0f) * invj + 128.0f;
        float jmn = fminf(jA, jB) - 1.0f;   // widen: weights self-guard extras
        float jmx = fmaxf(jA, jB) + 2.0f;
        jl = (int)fminf(fmaxf(jmn, 0.0f), 256.0f);
        jh = (int)fminf(fmaxf(jmx, 0.0f), 256.0f);
    } else {                               // cj ~ 0: t j-independent
        bool any = (363.0f + q > rf - 1.01f) && (363.0f + p < rf + 1.01f);
        jl = 0; jh = any ? 256 : 0;
    }
    if (!active) { jl = 0; jh = 0; }

    // parity strip: EXACT disjoint partition, no boundary arithmetic
    int start = jl + ((jl ^ m) & 1);       // first row >= jl with parity m

    // lower i-edge of the |u|<1 window: L(j) = LO0 + j*dlo; u(L) = sgn
    float inv  = 1.0f / ci;                // |ci| >= 0.707
    float sgn  = (ci > 0.0f) ? -1.0f : 1.0f;
    float Z0   = 363.0f - rf - 128.0f * cj - 128.0f * ci;
    float LO0  = (sgn - Z0) * inv;
    float dlo  = -cj * inv;                // |dlo| <= 1
    float onems = 1.0f - sgn;              // 2 (ci>0) or 0 (ci<0)
    float onepls = 1.0f + sgn;             // 0 (ci>0) or 2 (ci<0)
    float dlo2 = dlo + dlo;

    int wid = tid >> 6, lane = tid & 63;
    float acc0 = 0.0f, acc1 = 0.0f;
    for (int ph = 0; ph < NPH; ++ph) {
        int phb   = ph * PH_ROWS;
        int nrows = (phb + PH_ROWS <= 256) ? PH_ROWS : (256 - phb);
        if (ph) __syncthreads();           // prior-phase LDS reads complete
        // stage: one wave stages one 256-float row (64 lanes x 16B);
        // dest base = tile + sl*260 floats = sl*1040 B (16B-aligned)
        for (int sl = wid; sl < nrows; sl += 12) {
            const float* grow = src + (size_t)(phb + sl) * 256 + lane * 4;
            float* lrow = tile + sl * ROWSTR + lane * 4;
            __builtin_amdgcn_global_load_lds(
                (const __attribute__((address_space(1))) unsigned int*)grow,
                (__attribute__((address_space(3))) unsigned int*)lrow, 16, 0, 0);
        }
        __syncthreads();                   // staging complete (vmcnt drained)

        // this lane's parity-m rows within the phase band
        int pstart = phb + ((phb ^ m) & 1);
        int jsp = start > pstart ? start : pstart;
        int jep = jh < phb + nrows ? jh : phb + nrows;
        if (jep <= jsp) continue;
        int cnt = (jep - jsp + 1) >> 1;    // rows: jsp, jsp+2, ...

        float lo = fmaf((float)jsp, dlo, LO0);
        int rowf = (jsp - phb) * ROWSTR;
        int nq = cnt >> 2;
        for (int qd = 0; qd < nq; ++qd) {
            float lo0 = lo;
            float lo1 = lo0 + dlo2;
            float lo2 = lo1 + dlo2;
            float lo3 = lo2 + dlo2;
            lo = lo3 + dlo2;
            float f0 = __builtin_amdgcn_fmed3f(ceilf(lo0), 0.0f, 253.0f);
            float f1 = __builtin_amdgcn_fmed3f(ceilf(lo1), 0.0f, 253.0f);
            float f2 = __builtin_amdgcn_fmed3f(ceilf(lo2), 0.0f, 253.0f);
            float f3 = __builtin_amdgcn_fmed3f(ceilf(lo3), 0.0f, 253.0f);
            int i0 = (int)f0, i1 = (int)f1, i2 = (int)f2, i3 = (int)f3;
            const float* P0 = tile + rowf + i0;
            const float* P1 = tile + rowf + 2 * ROWSTR + i1;
            const float* P2 = tile + rowf + 4 * ROWSTR + i2;
            const float* P3 = tile + rowf + 6 * ROWSTR + i3;
            rowf += 8 * ROWSTR;
            // issue all 12 tap reads before consuming (MLP)
            float v00 = P0[0], v01 = P0[1], v02 = P0[2];
            float v10 = P1[0], v11 = P1[1], v12 = P1[2];
            float v20 = P2[0], v21 = P2[1], v22 = P2[2];
            float v30 = P3[0], v31 = P3[1], v32 = P3[2];
            // two independent accumulator chains
            acc0 = tap3(f0, lo0, ci, onems, onepls, v00, v01, v02, acc0);
            acc1 = tap3(f1, lo1, ci, onems, onepls, v10, v11, v12, acc1);
            acc0 = tap3(f2, lo2, ci, onems, onepls, v20, v21, v22, acc0);
            acc1 = tap3(f3, lo3, ci, onems, onepls, v30, v31, v32, acc1);
        }
        int rem = cnt & 3;
        for (int t = 0; t < rem; ++t) {    // tail: <=3 parity rows
            float f0 = __builtin_amdgcn_fmed3f(ceilf(lo), 0.0f, 253.0f);
            int   i0 = (int)f0;
            const float* P0 = tile + rowf + i0;
            float v00 = P0[0], v01 = P0[1], v02 = P0[2];
            acc0 = tap3(f0, lo, ci, onems, onepls, v00, v01, v02, acc0);
            lo += dlo2; rowf += 2 * ROWSTR;
        }
    }

    // reduce the 2 parity strips (adjacent lanes), lane m==0 stores
    float acc = acc0 + acc1;
    acc += __shfl_xor(acc, 1);
    if (active && m == 0)
        out[(size_t)ba * RBINS + r] = acc;
}

// ---------------- fallback (no workspace): R7-proven global-gather ----------------
typedef float f3v __attribute__((ext_vector_type(3)));
typedef f3v __attribute__((aligned(4))) f3u;
#define FB_GRP (368 * 4)

__global__ __launch_bounds__(256) void hough_fb_k(const float* __restrict__ src0,
                                                  float* __restrict__ out, int nba) {
    int gtid = blockIdx.x * 256 + threadIdx.x;
    int grp  = gtid / FB_GRP;
    if (grp >= nba) return;
    int k    = gtid - grp * FB_GRP;
    int ba   = __builtin_amdgcn_readfirstlane(grp);
    int b    = ba / NUM_A;
    int a    = ba - b * NUM_A;
    double th = (double)a * (3.14159265358979323846 / 90.0);
    float c = (float)cos(th), s = (float)sin(th);
    bool  xs = fabsf(c) >= fabsf(s);
    float ci = xs ? c : s, cj = xs ? s : c;
    const float* src = src0 + (size_t)b * (HDIM * WDIM);
    int   bin = k >> 2, m = k & 3;
    int   r = RMIN + bin;
    float rf = (float)r;
    bool  active = bin < RACT;
    float inv = 1.0f / ci, ainv = fabsf(inv);
    float p = fminf(-128.0f * ci, 127.0f * ci);
    float q = fmaxf(-128.0f * ci, 127.0f * ci);
    int jl, jh;
    float acj = fabsf(cj);
    if (acj > 1e-5f) {
        float invj = 1.0f / cj;
        float jA = (rf + 1.0f - p - 363.0f) * invj + 128.0f;
        float jB = (rf - 1.0f - q - 363.0f) * invj + 128.0f;
        jl = (int)fminf(fmaxf(fminf(jA, jB) - 1.0f, 0.0f), 256.0f);
        jh = (int)fminf(fmaxf(fmaxf(jA, jB) + 2.0f, 0.0f), 256.0f);
    } else {
        bool any = (363.0f + q > rf - 1.01f) && (363.0f + p < rf + 1.01f);
        jl = 0; jh = any ? 256 : 0;
    }
    if (!active) { jl = 0; jh = 0; }
    int len = jh - jl;
    int js = jl + ((m * len) >> 2);
    int je = jl + (((m + 1) * len) >> 2);
    float dlo = -cj * inv;
    float LO0 = 128.0f + (rf - 363.0f) * inv - ainv + 128.0f * cj * inv;
    float Z0  = 363.0f - rf - 128.0f * cj - 128.0f * ci;
    float ci2 = ci + ci;
    float acc = 0.0f;
    for (int j = js; j < je; ++j) {
        float jf  = (float)j;
        float lo0 = fmaf(jf, dlo, LO0);
        float z0  = fmaf(jf, cj, Z0);
        float f0  = __builtin_amdgcn_fmed3f(ceilf(lo0), 0.0f, 253.0f);
        int   i0  = (int)f0;
        float a0, b0, c0;
        if (xs) {
            f3v mm = *(const f3u*)(src + ((size_t)j << 8) + i0);
            a0 = mm.x; b0 = mm.y; c0 = mm.z;
        } else {
            const float* p0 = src + j + ((size_t)i0 << 8);
            a0 = p0[0]; b0 = p0[256]; c0 = p0[512];
        }
        float u0 = fmaf(f0, ci, z0);
        acc = fmaf(a0, fmaxf(1.0f - fabsf(u0), 0.0f), acc);
        acc = fmaf(b0, fmaxf(1.0f - fabsf(u0 + ci), 0.0f), acc);
        acc = fmaf(c0, fmaxf(1.0f - fabsf(u0 + ci2), 0.0f), acc);
    }
    acc += __shfl_xor(acc, 1);
    acc += __shfl_xor(acc, 2);
    if (active && m == 0)
        out[(size_t)ba * RBINS + r] = acc;
}

extern "C" void kernel_launch(void* const* d_in, const int* in_sizes, int n_in,
                              void* d_out, int out_size, void* d_ws, size_t ws_size,
                              hipStream_t stream) {
    const float* mask = (const float*)d_in[0];
    float* out = (float*)d_out;
    int B = in_sizes[0] / (HDIM * WDIM);   // 16
    int nba = B * NUM_A;

    size_t needT = (size_t)B * HDIM * WDIM * sizeof(float);
    size_t needW = needT + 2 * NUM_A * sizeof(float);
    int fast = (d_ws != nullptr && ws_size >= needW) ? 1 : 0;
    float* maskT = (float*)d_ws;
    float* tab   = (float*)((char*)d_ws + needT);

    // zero the never-touched rho bins once per call (also covers len==0 bins)
    hipMemsetAsync(d_out, 0, (size_t)out_size * sizeof(float), stream);

    if (fast) {
        transpose_k<<<dim3(WDIM / 32, HDIM / 32, B), dim3(32, 8), 0, stream>>>(mask, maskT);
        angles_k<<<1, 128, 0, stream>>>(tab);
        hough_lds_k<<<nba, TPB, 0, stream>>>(mask, maskT, tab, out);
    } else {
        int nthreads = nba * FB_GRP;
        hough_fb_k<<<(nthreads + 255) / 256, 256, 0, stream>>>(mask, out, nba);
    }
}

// Round 16
// 79.590 us; speedup vs baseline: 1.0925x; 1.0315x over previous
//
#include <hip/hip_runtime.h>
#include <math.h>

#define NUM_A 90
#define RBINS 727      // 2*363 + 1
#define HDIM  256
#define WDIM  256
#define RMIN  181      // lowest bin ever touched
#define RACT  365      // active bins: 181..545
#define TPB   768      // 368 bins x 2 parity-strips (+pad) = 12 waves
#define PH_ROWS 52
#define ROWSTR  260    // floats per row slot; 1040 B (16B-aligned); 260 % 32 = 4
#define NPH     5      // 52*4 + 48 = 256
#define TILE_N  (PH_ROWS * ROWSTR)   // 13520 floats = 54080 B

// ---------------- angle table: tab[2a]=cos, tab[2a+1]=sin ----------------
__global__ void angles_k(float* __restrict__ tab) {
    int a = threadIdx.x;
    if (a < NUM_A) {
        double th = (double)a * (3.14159265358979323846 / 90.0);
        tab[2 * a]     = (float)cos(th);
        tab[2 * a + 1] = (float)sin(th);
    }
}

// ---------------- transpose: maskT[b][x][y] = mask[b][y][x] ----------------
__global__ __launch_bounds__(256) void transpose_k(const float* __restrict__ in,
                                                   float* __restrict__ out) {
    __shared__ float tile[32][33];
    int b = blockIdx.z;
    const float* ib = in  + (size_t)b * (HDIM * WDIM);
    float*       ob = out + (size_t)b * (HDIM * WDIM);
    int x0 = blockIdx.x * 32, y0 = blockIdx.y * 32;
    int tx = threadIdx.x, ty = threadIdx.y;
#pragma unroll
    for (int j = ty; j < 32; j += 8)
        tile[j][tx] = ib[(size_t)(y0 + j) * WDIM + (x0 + tx)];
    __syncthreads();
#pragma unroll
    for (int j = ty; j < 32; j += 8)
        ob[(size_t)(x0 + j) * HDIM + (y0 + tx)] = tile[tx][j];
}

// 3-tap weight+accumulate: w_k = med3(1-u_k, 1+u_k, 0), u from fr = f0 - lo
// (exact). R11/R13-proven (absmax 1.0, graph-replay stable).
static __device__ __forceinline__ float tap3(float f0, float lo, float ci,
                                             float onems, float onepls,
                                             float v0, float v1, float v2,
                                             float acc) {
    float fr = f0 - lo;
    float a0 = fmaf(fr, -ci, onems), b0 = fmaf(fr, ci, onepls);
    acc = fmaf(v0, __builtin_amdgcn_fmed3f(a0, b0, 0.0f), acc);
    float a1 = a0 - ci, b1 = b0 + ci;
    acc = fmaf(v1, __builtin_amdgcn_fmed3f(a1, b1, 0.0f), acc);
    float a2 = a1 - ci, b2 = b1 + ci;
    acc = fmaf(v2, __builtin_amdgcn_fmed3f(a2, b2, 0.0f), acc);
    return acc;
}

// ---------------- LDS-staged gather hough (R13 structure + dual acc) ----------
__global__ __launch_bounds__(TPB, 6) void hough_lds_k(const float* __restrict__ srcA,
                                                      const float* __restrict__ srcB,
                                                      const float* __restrict__ tab,
                                                      float* __restrict__ out) {
    __shared__ float tile[TILE_N];
    int ba = blockIdx.x;
    int b  = ba / NUM_A;
    int a  = ba - b * NUM_A;

    float c = tab[2 * a], s = tab[2 * a + 1];
    bool  xs = fabsf(c) >= fabsf(s);       // solve axis = larger coeff
    float ci = xs ? c : s;
    float cj = xs ? s : c;
    const float* src = (xs ? srcA : srcB) + (size_t)b * (HDIM * WDIM);

    int   tid = threadIdx.x;
    int   bin = tid >> 1;                  // 2 parity strips per bin
    int   m   = tid & 1;                   // lane parity: rows j with (j&1)==m
    int   r   = RMIN + bin;
    float rf  = (float)r;
    bool  active = bin < RACT;

    // active j-range (R8/R11-proven): rows whose t-span hits (r-1, r+1)
    float p = fminf(-128.0f * ci, 127.0f * ci);
    float q = fmaxf(-128.0f * ci, 127.0f * ci);
    int jl, jh;
    float acj = fabsf(cj);
    if (acj > 1e-5f) {
        float invj = 1.0f / cj;
        float jA = (rf + 1.0f - p - 363.0f) * invj + 128.0f;
        float jB = (rf - 1.0f - q - 363.0f) * invj + 128.0f;
        float jmn = fminf(jA, jB) - 1.0f;   // widen: weights self-guard extras
        float jmx = fmaxf(jA, jB) + 2.0f;
        jl = (int)fminf(fmaxf(jmn, 0.0f), 256.0f);
        jh = (int)fminf(fmaxf(jmx, 0.0f), 256.0f);
    } else {                               // cj ~ 0: t j-independent
        bool any = (363.0f + q > rf - 1.01f) && (363.0f + p < rf + 1.01f);
        jl = 0; jh = any ? 256 : 0;
    }
    if (!active) { jl = 0; jh = 0; }

    // parity strip: EXACT disjoint partition, no boundary arithmetic
    int start = jl + ((jl ^ m) & 1);       // first row >= jl with parity m

    // lower i-edge of the |u|<1 window: L(j) = LO0 + j*dlo; u(L) = sgn
    float inv  = 1.0f / ci;                // |ci| >= 0.707
    float sgn  = (ci > 0.0f) ? -1.0f : 1.0f;
    float Z0   = 363.0f - rf - 128.0f * cj - 128.0f * ci;
    float LO0  = (sgn - Z0) * inv;
    float dlo  = -cj * inv;                // |dlo| <= 1
    float onems = 1.0f - sgn;              // 2 (ci>0) or 0 (ci<0)
    float onepls = 1.0f + sgn;             // 0 (ci>0) or 2 (ci<0)
    float dlo2 = dlo + dlo;

    int wid = tid >> 6, lane = tid & 63;
    float acc0 = 0.0f, acc1 = 0.0f;
    for (int ph = 0; ph < NPH; ++ph) {
        int phb   = ph * PH_ROWS;
        int nrows = (phb + PH_ROWS <= 256) ? PH_ROWS : (256 - phb);
        if (ph) __syncthreads();           // prior-phase LDS reads complete
        // stage: one wave stages one 256-float row (64 lanes x 16B);
        // dest base = tile + sl*260 floats = sl*1040 B (16B-aligned)
        for (int sl = wid; sl < nrows; sl += 12) {
            const float* grow = src + (size_t)(phb + sl) * 256 + lane * 4;
            float* lrow = tile + sl * ROWSTR + lane * 4;
            __builtin_amdgcn_global_load_lds(
                (const __attribute__((address_space(1))) unsigned int*)grow,
                (__attribute__((address_space(3))) unsigned int*)lrow, 16, 0, 0);
        }
        __syncthreads();                   // staging complete (vmcnt drained)

        // this lane's parity-m rows within the phase band
        int pstart = phb + ((phb ^ m) & 1);
        int jsp = start > pstart ? start : pstart;
        int jep = jh < phb + nrows ? jh : phb + nrows;
        if (jep <= jsp) continue;
        int cnt = (jep - jsp + 1) >> 1;    // rows: jsp, jsp+2, ...

        float lo = fmaf((float)jsp, dlo, LO0);
        int rowf = (jsp - phb) * ROWSTR;
        int npair = cnt >> 1;
        for (int pr = 0; pr < npair; ++pr) {
            float lo0 = lo;
            float lo1 = lo + dlo2;
            lo = lo1 + dlo2;
            float f0 = __builtin_amdgcn_fmed3f(ceilf(lo0), 0.0f, 253.0f);
            float f1 = __builtin_amdgcn_fmed3f(ceilf(lo1), 0.0f, 253.0f);
            int i0 = (int)f0, i1 = (int)f1;
            const float* p0 = tile + rowf + i0;
            const float* p1 = tile + rowf + 2 * ROWSTR + i1;
            rowf += 4 * ROWSTR;
            float v00 = p0[0], v01 = p0[1], v02 = p0[2];
            float v10 = p1[0], v11 = p1[1], v12 = p1[2];
            // independent accumulator chains (only delta vs R13)
            acc0 = tap3(f0, lo0, ci, onems, onepls, v00, v01, v02, acc0);
            acc1 = tap3(f1, lo1, ci, onems, onepls, v10, v11, v12, acc1);
        }
        if (cnt & 1) {                     // tail: one row
            float f0 = __builtin_amdgcn_fmed3f(ceilf(lo), 0.0f, 253.0f);
            int   i0 = (int)f0;
            const float* p0 = tile + rowf + i0;
            float v00 = p0[0], v01 = p0[1], v02 = p0[2];
            acc0 = tap3(f0, lo, ci, onems, onepls, v00, v01, v02, acc0);
        }
    }

    // reduce the 2 parity strips (adjacent lanes), lane m==0 stores
    float acc = acc0 + acc1;
    acc += __shfl_xor(acc, 1);
    if (active && m == 0)
        out[(size_t)ba * RBINS + r] = acc;
}

// ---------------- fallback (no workspace): R7-proven global-gather ----------------
typedef float f3v __attribute__((ext_vector_type(3)));
typedef f3v __attribute__((aligned(4))) f3u;
#define FB_GRP (368 * 4)

__global__ __launch_bounds__(256) void hough_fb_k(const float* __restrict__ src0,
                                                  float* __restrict__ out, int nba) {
    int gtid = blockIdx.x * 256 + threadIdx.x;
    int grp  = gtid / FB_GRP;
    if (grp >= nba) return;
    int k    = gtid - grp * FB_GRP;
    int ba   = __builtin_amdgcn_readfirstlane(grp);
    int b    = ba / NUM_A;
    int a    = ba - b * NUM_A;
    double th = (double)a * (3.14159265358979323846 / 90.0);
    float c = (float)cos(th), s = (float)sin(th);
    bool  xs = fabsf(c) >= fabsf(s);
    float ci = xs ? c : s, cj = xs ? s : c;
    const float* src = src0 + (size_t)b * (HDIM * WDIM);
    int   bin = k >> 2, m = k & 3;
    int   r = RMIN + bin;
    float rf = (float)r;
    bool  active = bin < RACT;
    float inv = 1.0f / ci, ainv = fabsf(inv);
    float p = fminf(-128.0f * ci, 127.0f * ci);
    float q = fmaxf(-128.0f * ci, 127.0f * ci);
    int jl, jh;
    float acj = fabsf(cj);
    if (acj > 1e-5f) {
        float invj = 1.0f / cj;
        float jA = (rf + 1.0f - p - 363.0f) * invj + 128.0f;
        float jB = (rf - 1.0f - q - 363.0f) * invj + 128.0f;
        jl = (int)fminf(fmaxf(fminf(jA, jB) - 1.0f, 0.0f), 256.0f);
        jh = (int)fminf(fmaxf(fmaxf(jA, jB) + 2.0f, 0.0f), 256.0f);
    } else {
        bool any = (363.0f + q > rf - 1.01f) && (363.0f + p < rf + 1.01f);
        jl = 0; jh = any ? 256 : 0;
    }
    if (!active) { jl = 0; jh = 0; }
    int len = jh - jl;
    int js = jl + ((m * len) >> 2);
    int je = jl + (((m + 1) * len) >> 2);
    float dlo = -cj * inv;
    float LO0 = 128.0f + (rf - 363.0f) * inv - ainv + 128.0f * cj * inv;
    float Z0  = 363.0f - rf - 128.0f * cj - 128.0f * ci;
    float ci2 = ci + ci;
    float acc = 0.0f;
    for (int j = js; j < je; ++j) {
        float jf  = (float)j;
        float lo0 = fmaf(jf, dlo, LO0);
        float z0  = fmaf(jf, cj, Z0);
        float f0  = __builtin_amdgcn_fmed3f(ceilf(lo0), 0.0f, 253.0f);
        int   i0  = (int)f0;
        float a0, b0, c0;
        if (xs) {
            f3v mm = *(const f3u*)(src + ((size_t)j << 8) + i0);
            a0 = mm.x; b0 = mm.y; c0 = mm.z;
        } else {
            const float* p0 = src + j + ((size_t)i0 << 8);
            a0 = p0[0]; b0 = p0[256]; c0 = p0[512];
        }
        float u0 = fmaf(f0, ci, z0);
        acc = fmaf(a0, fmaxf(1.0f - fabsf(u0), 0.0f), acc);
        acc = fmaf(b0, fmaxf(1.0f - fabsf(u0 + ci), 0.0f), acc);
        acc = fmaf(c0, fmaxf(1.0f - fabsf(u0 + ci2), 0.0f), acc);
    }
    acc += __shfl_xor(acc, 1);
    acc += __shfl_xor(acc, 2);
    if (active && m == 0)
        out[(size_t)ba * RBINS + r] = acc;
}

extern "C" void kernel_launch(void* const* d_in, const int* in_sizes, int n_in,
                              void* d_out, int out_size, void* d_ws, size_t ws_size,
                              hipStream_t stream) {
    const float* mask = (const float*)d_in[0];
    float* out = (float*)d_out;
    int B = in_sizes[0] / (HDIM * WDIM);   // 16
    int nba = B * NUM_A;

    size_t needT = (size_t)B * HDIM * WDIM * sizeof(float);
    size_t needW = needT + 2 * NUM_A * sizeof(float);
    int fast = (d_ws != nullptr && ws_size >= needW) ? 1 : 0;
    float* maskT = (float*)d_ws;
    float* tab   = (float*)((char*)d_ws + needT);

    // zero the never-touched rho bins once per call (also covers len==0 bins)
    hipMemsetAsync(d_out, 0, (size_t)out_size * sizeof(float), stream);

    if (fast) {
        transpose_k<<<dim3(WDIM / 32, HDIM / 32, B), dim3(32, 8), 0, stream>>>(mask, maskT);
        angles_k<<<1, 128, 0, stream>>>(tab);
        hough_lds_k<<<nba, TPB, 0, stream>>>(mask, maskT, tab, out);
    } else {
        int nthreads = nba * FB_GRP;
        hough_fb_k<<<(nthreads + 255) / 256, 256, 0, stream>>>(mask, out, nba);
    }
}

// Round 17
// 74.906 us; speedup vs baseline: 1.1608x; 1.0625x over previous
//
#include <hip/hip_runtime.h>
#include <math.h>

#define NUM_A 90
#define RBINS 727      // 2*363 + 1
#define HDIM  256
#define WDIM  256
#define RMIN  181      // lowest bin ever touched
#define RACT  365      // active bins: 181..545
#define TPB   768      // 368 bins x 2 parity-strips (+pad) = 12 waves
#define PH_ROWS 52
#define ROWSTR  260    // floats per row slot; 1040 B (16B-aligned); 260 % 32 = 4
#define NPH     5      // 52*4 + 48 = 256
#define TILE_N  (PH_ROWS * ROWSTR)   // 13520 floats = 54080 B

// ---------------- angle table: tab[2a]=cos, tab[2a+1]=sin ----------------
__global__ void angles_k(float* __restrict__ tab) {
    int a = threadIdx.x;
    if (a < NUM_A) {
        double th = (double)a * (3.14159265358979323846 / 90.0);
        tab[2 * a]     = (float)cos(th);
        tab[2 * a + 1] = (float)sin(th);
    }
}

// ---------------- transpose: maskT[b][x][y] = mask[b][y][x] ----------------
__global__ __launch_bounds__(256) void transpose_k(const float* __restrict__ in,
                                                   float* __restrict__ out) {
    __shared__ float tile[32][33];
    int b = blockIdx.z;
    const float* ib = in  + (size_t)b * (HDIM * WDIM);
    float*       ob = out + (size_t)b * (HDIM * WDIM);
    int x0 = blockIdx.x * 32, y0 = blockIdx.y * 32;
    int tx = threadIdx.x, ty = threadIdx.y;
#pragma unroll
    for (int j = ty; j < 32; j += 8)
        tile[j][tx] = ib[(size_t)(y0 + j) * WDIM + (x0 + tx)];
    __syncthreads();
#pragma unroll
    for (int j = ty; j < 32; j += 8)
        ob[(size_t)(x0 + j) * HDIM + (y0 + tx)] = tile[tx][j];
}

// 3-tap weight+accumulate: w_k = med3(1-u_k, 1+u_k, 0), u from fr = f0 - lo
// (exact). R11/R13-proven (absmax 1.0, graph-replay stable).
static __device__ __forceinline__ float tap3(float f0, float lo, float ci,
                                             float onems, float onepls,
                                             float v0, float v1, float v2,
                                             float acc) {
    float fr = f0 - lo;
    float a0 = fmaf(fr, -ci, onems), b0 = fmaf(fr, ci, onepls);
    acc = fmaf(v0, __builtin_amdgcn_fmed3f(a0, b0, 0.0f), acc);
    float a1 = a0 - ci, b1 = b0 + ci;
    acc = fmaf(v1, __builtin_amdgcn_fmed3f(a1, b1, 0.0f), acc);
    float a2 = a1 - ci, b2 = b1 + ci;
    acc = fmaf(v2, __builtin_amdgcn_fmed3f(a2, b2, 0.0f), acc);
    return acc;
}

// ---------------- LDS-staged gather hough (R13: R11 math + parity strips + 260 stride)
__global__ __launch_bounds__(TPB, 6) void hough_lds_k(const float* __restrict__ srcA,
                                                      const float* __restrict__ srcB,
                                                      const float* __restrict__ tab,
                                                      float* __restrict__ out) {
    __shared__ float tile[TILE_N];
    int ba = blockIdx.x;
    int b  = ba / NUM_A;
    int a  = ba - b * NUM_A;

    float c = tab[2 * a], s = tab[2 * a + 1];
    bool  xs = fabsf(c) >= fabsf(s);       // solve axis = larger coeff
    float ci = xs ? c : s;
    float cj = xs ? s : c;
    const float* src = (xs ? srcA : srcB) + (size_t)b * (HDIM * WDIM);

    int   tid = threadIdx.x;
    int   bin = tid >> 1;                  // 2 parity strips per bin
    int   m   = tid & 1;                   // lane parity: rows j with (j&1)==m
    int   r   = RMIN + bin;
    float rf  = (float)r;
    bool  active = bin < RACT;

    // active j-range (R8/R11-proven): rows whose t-span hits (r-1, r+1)
    float p = fminf(-128.0f * ci, 127.0f * ci);
    float q = fmaxf(-128.0f * ci, 127.0f * ci);
    int jl, jh;
    float acj = fabsf(cj);
    if (acj > 1e-5f) {
        float invj = 1.0f / cj;
        float jA = (rf + 1.0f - p - 363.0f) * invj + 128.0f;
        float jB = (rf - 1.0f - q - 363.0f) * invj + 128.0f;
        float jmn = fminf(jA, jB) - 1.0f;   // widen: weights self-guard extras
        float jmx = fmaxf(jA, jB) + 2.0f;
        jl = (int)fminf(fmaxf(jmn, 0.0f), 256.0f);
        jh = (int)fminf(fmaxf(jmx, 0.0f), 256.0f);
    } else {                               // cj ~ 0: t j-independent
        bool any = (363.0f + q > rf - 1.01f) && (363.0f + p < rf + 1.01f);
        jl = 0; jh = any ? 256 : 0;
    }
    if (!active) { jl = 0; jh = 0; }

    // parity strip: EXACT disjoint partition, no boundary arithmetic
    int start = jl + ((jl ^ m) & 1);       // first row >= jl with parity m

    // lower i-edge of the |u|<1 window: L(j) = LO0 + j*dlo; u(L) = sgn
    float inv  = 1.0f / ci;                // |ci| >= 0.707
    float sgn  = (ci > 0.0f) ? -1.0f : 1.0f;
    float Z0   = 363.0f - rf - 128.0f * cj - 128.0f * ci;
    float LO0  = (sgn - Z0) * inv;
    float dlo  = -cj * inv;                // |dlo| <= 1
    float onems = 1.0f - sgn;              // 2 (ci>0) or 0 (ci<0)
    float onepls = 1.0f + sgn;             // 0 (ci>0) or 2 (ci<0)
    float dlo2 = dlo + dlo;

    int wid = tid >> 6, lane = tid & 63;
    float acc = 0.0f;
    for (int ph = 0; ph < NPH; ++ph) {
        int phb   = ph * PH_ROWS;
        int nrows = (phb + PH_ROWS <= 256) ? PH_ROWS : (256 - phb);
        if (ph) __syncthreads();           // prior-phase LDS reads complete
        // stage: one wave stages one 256-float row (64 lanes x 16B);
        // dest base = tile + sl*260 floats = sl*1040 B (16B-aligned)
        for (int sl = wid; sl < nrows; sl += 12) {
            const float* grow = src + (size_t)(phb + sl) * 256 + lane * 4;
            float* lrow = tile + sl * ROWSTR + lane * 4;
            __builtin_amdgcn_global_load_lds(
                (const __attribute__((address_space(1))) unsigned int*)grow,
                (__attribute__((address_space(3))) unsigned int*)lrow, 16, 0, 0);
        }
        __syncthreads();                   // staging complete (vmcnt drained)

        // this lane's parity-m rows within the phase band
        int pstart = phb + ((phb ^ m) & 1);
        int jsp = start > pstart ? start : pstart;
        int jep = jh < phb + nrows ? jh : phb + nrows;
        if (jep <= jsp) continue;
        int cnt = (jep - jsp + 1) >> 1;    // rows: jsp, jsp+2, ...

        float lo = fmaf((float)jsp, dlo, LO0);
        int rowf = (jsp - phb) * ROWSTR;
        int npair = cnt >> 1;
        for (int pr = 0; pr < npair; ++pr) {
            float lo0 = lo;
            float lo1 = lo + dlo2;
            lo = lo1 + dlo2;
            float f0 = __builtin_amdgcn_fmed3f(ceilf(lo0), 0.0f, 253.0f);
            float f1 = __builtin_amdgcn_fmed3f(ceilf(lo1), 0.0f, 253.0f);
            int i0 = (int)f0, i1 = (int)f1;
            const float* p0 = tile + rowf + i0;
            const float* p1 = tile + rowf + 2 * ROWSTR + i1;
            rowf += 4 * ROWSTR;
            float v00 = p0[0], v01 = p0[1], v02 = p0[2];
            float v10 = p1[0], v11 = p1[1], v12 = p1[2];
            acc = tap3(f0, lo0, ci, onems, onepls, v00, v01, v02, acc);
            acc = tap3(f1, lo1, ci, onems, onepls, v10, v11, v12, acc);
        }
        if (cnt & 1) {                     // tail: one row
            float f0 = __builtin_amdgcn_fmed3f(ceilf(lo), 0.0f, 253.0f);
            int   i0 = (int)f0;
            const float* p0 = tile + rowf + i0;
            float v00 = p0[0], v01 = p0[1], v02 = p0[2];
            acc = tap3(f0, lo, ci, onems, onepls, v00, v01, v02, acc);
        }
    }

    // reduce the 2 parity strips (adjacent lanes), lane m==0 stores
    acc += __shfl_xor(acc, 1);
    if (active && m == 0)
        out[(size_t)ba * RBINS + r] = acc;
}

// ---------------- fallback (no workspace): R7-proven global-gather ----------------
typedef float f3v __attribute__((ext_vector_type(3)));
typedef f3v __attribute__((aligned(4))) f3u;
#define FB_GRP (368 * 4)

__global__ __launch_bounds__(256) void hough_fb_k(const float* __restrict__ src0,
                                                  float* __restrict__ out, int nba) {
    int gtid = blockIdx.x * 256 + threadIdx.x;
    int grp  = gtid / FB_GRP;
    if (grp >= nba) return;
    int k    = gtid - grp * FB_GRP;
    int ba   = __builtin_amdgcn_readfirstlane(grp);
    int b    = ba / NUM_A;
    int a    = ba - b * NUM_A;
    double th = (double)a * (3.14159265358979323846 / 90.0);
    float c = (float)cos(th), s = (float)sin(th);
    bool  xs = fabsf(c) >= fabsf(s);
    float ci = xs ? c : s, cj = xs ? s : c;
    const float* src = src0 + (size_t)b * (HDIM * WDIM);
    int   bin = k >> 2, m = k & 3;
    int   r = RMIN + bin;
    float rf = (float)r;
    bool  active = bin < RACT;
    float inv = 1.0f / ci, ainv = fabsf(inv);
    float p = fminf(-128.0f * ci, 127.0f * ci);
    float q = fmaxf(-128.0f * ci, 127.0f * ci);
    int jl, jh;
    float acj = fabsf(cj);
    if (acj > 1e-5f) {
        float invj = 1.0f / cj;
        float jA = (rf + 1.0f - p - 363.0f) * invj + 128.0f;
        float jB = (rf - 1.0f - q - 363.0f) * invj + 128.0f;
        jl = (int)fminf(fmaxf(fminf(jA, jB) - 1.0f, 0.0f), 256.0f);
        jh = (int)fminf(fmaxf(fmaxf(jA, jB) + 2.0f, 0.0f), 256.0f);
    } else {
        bool any = (363.0f + q > rf - 1.01f) && (363.0f + p < rf + 1.01f);
        jl = 0; jh = any ? 256 : 0;
    }
    if (!active) { jl = 0; jh = 0; }
    int len = jh - jl;
    int js = jl + ((m * len) >> 2);
    int je = jl + (((m + 1) * len) >> 2);
    float dlo = -cj * inv;
    float LO0 = 128.0f + (rf - 363.0f) * inv - ainv + 128.0f * cj * inv;
    float Z0  = 363.0f - rf - 128.0f * cj - 128.0f * ci;
    float ci2 = ci + ci;
    float acc = 0.0f;
    for (int j = js; j < je; ++j) {
        float jf  = (float)j;
        float lo0 = fmaf(jf, dlo, LO0);
        float z0  = fmaf(jf, cj, Z0);
        float f0  = __builtin_amdgcn_fmed3f(ceilf(lo0), 0.0f, 253.0f);
        int   i0  = (int)f0;
        float a0, b0, c0;
        if (xs) {
            f3v mm = *(const f3u*)(src + ((size_t)j << 8) + i0);
            a0 = mm.x; b0 = mm.y; c0 = mm.z;
        } else {
            const float* p0 = src + j + ((size_t)i0 << 8);
            a0 = p0[0]; b0 = p0[256]; c0 = p0[512];
        }
        float u0 = fmaf(f0, ci, z0);
        acc = fmaf(a0, fmaxf(1.0f - fabsf(u0), 0.0f), acc);
        acc = fmaf(b0, fmaxf(1.0f - fabsf(u0 + ci), 0.0f), acc);
        acc = fmaf(c0, fmaxf(1.0f - fabsf(u0 + ci2), 0.0f), acc);
    }
    acc += __shfl_xor(acc, 1);
    acc += __shfl_xor(acc, 2);
    if (active && m == 0)
        out[(size_t)ba * RBINS + r] = acc;
}

extern "C" void kernel_launch(void* const* d_in, const int* in_sizes, int n_in,
                              void* d_out, int out_size, void* d_ws, size_t ws_size,
                              hipStream_t stream) {
    const float* mask = (const float*)d_in[0];
    float* out = (float*)d_out;
    int B = in_sizes[0] / (HDIM * WDIM);   // 16
    int nba = B * NUM_A;

    size_t needT = (size_t)B * HDIM * WDIM * sizeof(float);
    size_t needW = needT + 2 * NUM_A * sizeof(float);
    int fast = (d_ws != nullptr && ws_size >= needW) ? 1 : 0;
    float* maskT = (float*)d_ws;
    float* tab   = (float*)((char*)d_ws + needT);

    // zero the never-touched rho bins once per call (also covers len==0 bins)
    hipMemsetAsync(d_out, 0, (size_t)out_size * sizeof(float), stream);

    if (fast) {
        transpose_k<<<dim3(WDIM / 32, HDIM / 32, B), dim3(32, 8), 0, stream>>>(mask, maskT);
        angles_k<<<1, 128, 0, stream>>>(tab);
        hough_lds_k<<<nba, TPB, 0, stream>>>(mask, maskT, tab, out);
    } else {
        int nthreads = nba * FB_GRP;
        hough_fb_k<<<(nthreads + 255) / 256, 256, 0, stream>>>(mask, out, nba);
    }
}